// Round 5
// baseline (139.511 us; speedup 1.0000x reference)
//
#include <hip/hip_runtime.h>
#include <hip/hip_bf16.h>

// BatchedExponentialOrthogonalization: res = sum_{i=0}^{6} S^i / i!,  S = 0.5(w - w^T)
// w: (512, 256, 256) fp32.  Horner: T = I + S/6; then T = I + (S/k)*T for k=5,4,3,2,1.
// prep: 5120 tile-pair blocks build S in bf16 into d_ws (64 MB), at HBM floor.
// main: per (batch, 64-col slab) workgroup, 4 waves; wave wv holds S rows
// [64wv,64wv+64) as 32x32x16 MFMA A-fragments in registers for all 5 iterations;
// T double-buffered in LDS transposed [col][k] bf16 with XOR bank swizzle.
// Round-5: 32x32x16 shape (4061 vs 3378 FLOP/cyc; write-path bank-conflict-free via
// the +4*(l>>5) row term) + depth-8 B-frag prefetch pipeline to cover LDS latency.

#define NB 512
#define NN 256

typedef __attribute__((ext_vector_type(8))) short bf16x8;
typedef __attribute__((ext_vector_type(16))) float f32x16;

__device__ __forceinline__ unsigned short f2bf(float x) {
  union { float f; unsigned int u; } v; v.f = x;
  unsigned int r = v.u + 0x7fffu + ((v.u >> 16) & 1u);  // RTNE
  return (unsigned short)(r >> 16);
}
__device__ __forceinline__ float bf2f(unsigned short u) {
  union { unsigned int u; float f; } v; v.u = ((unsigned int)u) << 16; return v.f;
}
__device__ __forceinline__ unsigned int pk2bf(float lo, float hi) {
  __hip_bfloat162 h;
  h.x = __float2bfloat16(lo);
  h.y = __float2bfloat16(hi);
  union { __hip_bfloat162 h; unsigned int u; } c; c.h = h;
  return c.u;
}

// ---------------- prep: S = 0.5*(w - w^T) in bf16; one block per 64x64 tile-pair ----
__global__ __launch_bounds__(256) void skew_prep_kernel(const float* __restrict__ w,
                                                        unsigned short* __restrict__ s) {
  static const int TI[10] = {0, 0, 0, 0, 1, 1, 1, 2, 2, 3};
  static const int TJ[10] = {0, 1, 2, 3, 1, 2, 3, 2, 3, 3};
  const int blk = blockIdx.x;
  const int b = blk / 10;
  const int p = blk - b * 10;
  const int ti = TI[p], tj = TJ[p];
  const float* wb = w + (size_t)b * NN * NN;
  unsigned short* sb = s + (size_t)b * NN * NN;
  __shared__ float ta[64][65];
  __shared__ float tb[64][65];
  const int tid = threadIdx.x;
  const int r = tid >> 4;
  const int c4 = tid & 15;

  #pragma unroll
  for (int e = 0; e < 4; ++e) {
    const int rr = e * 16 + r;
    float4 v = *(const float4*)&wb[(size_t)(ti * 64 + rr) * NN + tj * 64 + c4 * 4];
    ta[rr][c4 * 4 + 0] = v.x; ta[rr][c4 * 4 + 1] = v.y;
    ta[rr][c4 * 4 + 2] = v.z; ta[rr][c4 * 4 + 3] = v.w;
  }
  if (ti != tj) {
    #pragma unroll
    for (int e = 0; e < 4; ++e) {
      const int rr = e * 16 + r;
      float4 v = *(const float4*)&wb[(size_t)(tj * 64 + rr) * NN + ti * 64 + c4 * 4];
      tb[rr][c4 * 4 + 0] = v.x; tb[rr][c4 * 4 + 1] = v.y;
      tb[rr][c4 * 4 + 2] = v.z; tb[rr][c4 * 4 + 3] = v.w;
    }
  }
  __syncthreads();

  #pragma unroll
  for (int e = 0; e < 4; ++e) {
    const int rr = e * 16 + r;
    {
      unsigned short o[4];
      #pragma unroll
      for (int j = 0; j < 4; ++j) {
        const int cc = c4 * 4 + j;
        float av = ta[rr][cc];
        float bt = (ti == tj) ? ta[cc][rr] : tb[cc][rr];
        o[j] = f2bf(0.5f * (av - bt));
      }
      *(ushort4*)&sb[(size_t)(ti * 64 + rr) * NN + tj * 64 + c4 * 4] =
          make_ushort4(o[0], o[1], o[2], o[3]);
    }
    if (ti != tj) {
      unsigned short o[4];
      #pragma unroll
      for (int j = 0; j < 4; ++j) {
        const int cc = c4 * 4 + j;
        o[j] = f2bf(0.5f * (tb[rr][cc] - ta[cc][rr]));
      }
      *(ushort4*)&sb[(size_t)(tj * 64 + rr) * NN + ti * 64 + c4 * 4] =
          make_ushort4(o[0], o[1], o[2], o[3]);
    }
  }
}

// ---------------- main: Horner chain, 32x32x16 MFMA, S-rows in regs, T dbuf in LDS --
__global__ __launch_bounds__(256, 2) void expm_main_kernel(const unsigned short* __restrict__ s,
                                                           float* __restrict__ out) {
  // XCD-aware decode: all 4 col-slabs of batch b share (g mod 8) -> same XCD L2.
  const int g = blockIdx.x;
  const int b = ((g >> 5) << 3) | (g & 7);
  const int cb = (g >> 3) & 3;
  const int tid = threadIdx.x;
  const int wv = tid >> 6;
  const int l = tid & 63;
  const int l31 = l & 31;
  const int h = l >> 5;

  const unsigned short* sb = s + (size_t)b * NN * NN;
  // T buffers: [col 0..63][k 0..255] bf16, byte = col*512 + ((2k) ^ ((col&7)<<4))
  __shared__ alignas(16) unsigned char Tl[2][64 * NN * 2];

  // --- A fragments (32x32x16): wave wv owns S rows [64wv, 64wv+64).
  // a[mf][ks]: rows 32mf + l31, k = 16ks + 8h + {0..7}
  bf16x8 a[2][16];
  const int rbase = wv * 64;
  #pragma unroll
  for (int mf = 0; mf < 2; ++mf) {
    const bf16x8* p = (const bf16x8*)(sb + (size_t)(rbase + 32 * mf + l31) * NN);
    #pragma unroll
    for (int ks = 0; ks < 16; ++ks) a[mf][ks] = p[2 * ks + h];
  }

  // --- T init into buf0: T[k][gcol] = (k==gcol) - S[gcol][k]/6 (skew symmetry). ---
  if (wv == cb) {
    #pragma unroll
    for (int mf = 0; mf < 2; ++mf) {
      const int lc = 32 * mf + l31;
      const int gcol = rbase + lc;
      const int swz = (lc & 7) << 4;
      #pragma unroll
      for (int ks = 0; ks < 16; ++ks) {
        const bf16x8 fr = a[mf][ks];
        const int k0 = 16 * ks + 8 * h;
        unsigned int pk[4];
        #pragma unroll
        for (int q = 0; q < 4; ++q) {
          float v0 = (-1.0f / 6.0f) * bf2f((unsigned short)fr[2 * q]);
          float v1 = (-1.0f / 6.0f) * bf2f((unsigned short)fr[2 * q + 1]);
          if (k0 + 2 * q == gcol) v0 += 1.0f;
          if (k0 + 2 * q + 1 == gcol) v1 += 1.0f;
          pk[q] = pk2bf(v0, v1);
        }
        const int byte = lc * 512 + ((2 * k0) ^ swz);
        uint4 val; val.x = pk[0]; val.y = pk[1]; val.z = pk[2]; val.w = pk[3];
        *(uint4*)(&Tl[0][byte]) = val;
      }
    }
  }
  __syncthreads();

  float* const outb = out + (size_t)b * NN * NN + cb * 64;
  const bool diagw = (wv == cb);

  #pragma unroll
  for (int it = 0; it < 5; ++it) {
    const int rd = it & 1;        // compile-time after unroll
    const int wr = rd ^ 1;
    const float coef = (it == 0) ? 0.2f : (it == 1) ? 0.25f : (it == 2) ? (1.0f / 3.0f)
                     : (it == 3) ? 0.5f : 1.0f;
    #pragma unroll
    for (int p = 0; p < 2; ++p) {
      const int col = 32 * p + l31;          // this lane's T/output column (local)
      const int cswz = (col & 7) << 4;
      const int cbase = col * 512;

      f32x16 acc[2];
      #pragma unroll
      for (int mf = 0; mf < 2; ++mf)
        #pragma unroll
        for (int e = 0; e < 16; ++e) acc[mf][e] = 0.0f;

      // depth-8 prefetch pipeline of B fragments: b[ks] covers k = 16ks+8h+{0..7}
      bf16x8 bq[8];
      #pragma unroll
      for (int ks = 0; ks < 8; ++ks)
        bq[ks] = *(const bf16x8*)(&Tl[rd][cbase + ((32 * ks + 16 * h) ^ cswz)]);

      #pragma unroll
      for (int ks = 0; ks < 16; ++ks) {
        const bf16x8 bf = bq[ks & 7];
        if (ks + 8 < 16)
          bq[ks & 7] = *(const bf16x8*)(&Tl[rd][cbase + ((32 * (ks + 8) + 16 * h) ^ cswz)]);
        acc[0] = __builtin_amdgcn_mfma_f32_32x32x16_bf16(a[0][ks], bf, acc[0], 0, 0, 0);
        acc[1] = __builtin_amdgcn_mfma_f32_32x32x16_bf16(a[1][ks], bf, acc[1], 0, 0, 0);
      }

      if (it < 4) {
        // T_new[k=grow][col]: C layout row = (reg&3) + 8*(reg>>2) + 4h, col = l31
        #pragma unroll
        for (int mf = 0; mf < 2; ++mf) {
          #pragma unroll
          for (int q = 0; q < 4; ++q) {
            float v0 = coef * acc[mf][4 * q + 0];
            float v1 = coef * acc[mf][4 * q + 1];
            float v2 = coef * acc[mf][4 * q + 2];
            float v3 = coef * acc[mf][4 * q + 3];
            if (diagw && mf == p) {
              const int rl = 8 * q + 4 * h;  // local row within 32-tile, + j
              if (rl + 0 == l31) v0 += 1.0f;
              if (rl + 1 == l31) v1 += 1.0f;
              if (rl + 2 == l31) v2 += 1.0f;
              if (rl + 3 == l31) v3 += 1.0f;
            }
            const int kk = rbase + 32 * mf + 8 * q + 4 * h;
            const int byte = cbase + ((2 * kk) ^ cswz);
            uint2 val; val.x = pk2bf(v0, v1); val.y = pk2bf(v2, v3);
            *(uint2*)(&Tl[wr][byte]) = val;
          }
        }
      } else {
        // final iteration: res = I + S*T in fp32 straight to global
        #pragma unroll
        for (int mf = 0; mf < 2; ++mf) {
          #pragma unroll
          for (int q = 0; q < 4; ++q) {
            #pragma unroll
            for (int j = 0; j < 4; ++j) {
              float v = acc[mf][4 * q + j];
              if (diagw && mf == p && (8 * q + 4 * h + j == l31)) v += 1.0f;
              const int grow = rbase + 32 * mf + 8 * q + 4 * h + j;
              outb[(size_t)grow * NN + col] = v;
            }
          }
        }
      }
    }
    if (it < 4) __syncthreads();  // T_new complete before next iteration reads it
  }
}

extern "C" void kernel_launch(void* const* d_in, const int* in_sizes, int n_in,
                              void* d_out, int out_size, void* d_ws, size_t ws_size,
                              hipStream_t stream) {
  const float* w = (const float*)d_in[0];
  float* out = (float*)d_out;
  unsigned short* sws = (unsigned short*)d_ws;  // needs 512*256*256*2 = 64 MB
  skew_prep_kernel<<<dim3(NB * 10), dim3(256), 0, stream>>>(w, sws);
  expm_main_kernel<<<dim3(NB * 4), dim3(256), 0, stream>>>(sws, out);
}

// Round 6
// 123.066 us; speedup vs baseline: 1.1336x; 1.1336x over previous
//
#include <hip/hip_runtime.h>
#include <hip/hip_bf16.h>

// BatchedExponentialOrthogonalization: res = sum_{i=0}^{6} S^i / i!,  S = 0.5(w - w^T)
// w: (512, 256, 256) fp32.  Horner: T = I + S/6; then T = I + (S/k)*T for k=5,4,3,2,1.
// prep: 5120 tile-pair blocks build S in bf16 into d_ws (64 MB), at HBM floor.
// main (round-4 verified structure): per (batch, 64-col slab) workgroup, 4 waves;
// wave wv holds S rows [64wv,64wv+64) as 16x16x32 MFMA A-fragments in registers for
// all 5 iterations; T double-buffered in LDS transposed [col][k] bf16, XOR swizzle;
// one barrier/iter; nf split into 2 passes.
// Round-6 change: explicit 16-deep B-fragment prefetch per pass (bfr[8][2], 64 VGPR)
// so LDS read latency (~120cy) hides under the 312cy MFMA chain. Round-4's compiler
// schedule kept only 2 frags live (VGPR_Count 108) -> latency-bound at ~160cy/ks.
// (Round-5's 32x32 shape spilled: arch-VGPR split capped at 128; reverted.)

#define NB 512
#define NN 256

typedef __attribute__((ext_vector_type(8))) short bf16x8;
typedef __attribute__((ext_vector_type(4))) float f32x4;

__device__ __forceinline__ unsigned short f2bf(float x) {
  union { float f; unsigned int u; } v; v.f = x;
  unsigned int r = v.u + 0x7fffu + ((v.u >> 16) & 1u);  // RTNE
  return (unsigned short)(r >> 16);
}
__device__ __forceinline__ float bf2f(unsigned short u) {
  union { unsigned int u; float f; } v; v.u = ((unsigned int)u) << 16; return v.f;
}
__device__ __forceinline__ unsigned int pk2bf(float lo, float hi) {
  __hip_bfloat162 h;
  h.x = __float2bfloat16(lo);
  h.y = __float2bfloat16(hi);
  union { __hip_bfloat162 h; unsigned int u; } c; c.h = h;
  return c.u;
}

// ---------------- prep: S = 0.5*(w - w^T) in bf16; one block per 64x64 tile-pair ----
__global__ __launch_bounds__(256) void skew_prep_kernel(const float* __restrict__ w,
                                                        unsigned short* __restrict__ s) {
  static const int TI[10] = {0, 0, 0, 0, 1, 1, 1, 2, 2, 3};
  static const int TJ[10] = {0, 1, 2, 3, 1, 2, 3, 2, 3, 3};
  const int blk = blockIdx.x;
  const int b = blk / 10;
  const int p = blk - b * 10;
  const int ti = TI[p], tj = TJ[p];
  const float* wb = w + (size_t)b * NN * NN;
  unsigned short* sb = s + (size_t)b * NN * NN;
  __shared__ float ta[64][65];
  __shared__ float tb[64][65];
  const int tid = threadIdx.x;
  const int r = tid >> 4;
  const int c4 = tid & 15;

  #pragma unroll
  for (int e = 0; e < 4; ++e) {
    const int rr = e * 16 + r;
    float4 v = *(const float4*)&wb[(size_t)(ti * 64 + rr) * NN + tj * 64 + c4 * 4];
    ta[rr][c4 * 4 + 0] = v.x; ta[rr][c4 * 4 + 1] = v.y;
    ta[rr][c4 * 4 + 2] = v.z; ta[rr][c4 * 4 + 3] = v.w;
  }
  if (ti != tj) {
    #pragma unroll
    for (int e = 0; e < 4; ++e) {
      const int rr = e * 16 + r;
      float4 v = *(const float4*)&wb[(size_t)(tj * 64 + rr) * NN + ti * 64 + c4 * 4];
      tb[rr][c4 * 4 + 0] = v.x; tb[rr][c4 * 4 + 1] = v.y;
      tb[rr][c4 * 4 + 2] = v.z; tb[rr][c4 * 4 + 3] = v.w;
    }
  }
  __syncthreads();

  #pragma unroll
  for (int e = 0; e < 4; ++e) {
    const int rr = e * 16 + r;
    {
      unsigned short o[4];
      #pragma unroll
      for (int j = 0; j < 4; ++j) {
        const int cc = c4 * 4 + j;
        float av = ta[rr][cc];
        float bt = (ti == tj) ? ta[cc][rr] : tb[cc][rr];
        o[j] = f2bf(0.5f * (av - bt));
      }
      *(ushort4*)&sb[(size_t)(ti * 64 + rr) * NN + tj * 64 + c4 * 4] =
          make_ushort4(o[0], o[1], o[2], o[3]);
    }
    if (ti != tj) {
      unsigned short o[4];
      #pragma unroll
      for (int j = 0; j < 4; ++j) {
        const int cc = c4 * 4 + j;
        o[j] = f2bf(0.5f * (tb[rr][cc] - ta[cc][rr]));
      }
      *(ushort4*)&sb[(size_t)(tj * 64 + rr) * NN + ti * 64 + c4 * 4] =
          make_ushort4(o[0], o[1], o[2], o[3]);
    }
  }
}

// ---------------- main: Horner chain, S-rows in registers, T double-buffered in LDS --
__global__ __launch_bounds__(256, 2) void expm_main_kernel(const unsigned short* __restrict__ s,
                                                           float* __restrict__ out) {
  // XCD-aware decode: all 4 col-slabs of batch b share (g mod 8) -> same XCD L2.
  const int g = blockIdx.x;
  const int b = ((g >> 5) << 3) | (g & 7);
  const int cb = (g >> 3) & 3;
  const int tid = threadIdx.x;
  const int wv = tid >> 6;
  const int l = tid & 63;
  const int l15 = l & 15;
  const int l4 = l >> 4;

  const unsigned short* sb = s + (size_t)b * NN * NN;
  // T buffers: [col 0..63][k 0..255] bf16, byte addr = col*512 + ((2k) ^ ((col&7)<<4))
  __shared__ alignas(16) unsigned char Tl[2][64 * NN * 2];

  // --- A fragments: wave wv owns S rows [64*wv, 64*wv+64), persistent in registers ---
  bf16x8 a[4][8];
  const int rbase = wv * 64;
  #pragma unroll
  for (int mf = 0; mf < 4; ++mf) {
    const bf16x8* p = (const bf16x8*)(sb + (size_t)(rbase + 16 * mf + l15) * NN);
    #pragma unroll
    for (int ks = 0; ks < 8; ++ks) a[mf][ks] = p[4 * ks + l4];
  }

  // --- T init into buf0 from registers: T[k][gcol] = (k==gcol) - S[gcol][k]/6. ---
  if (wv == cb) {
    #pragma unroll
    for (int mf = 0; mf < 4; ++mf) {
      const int lc = 16 * mf + l15;
      const int gcol = rbase + lc;
      const int swz = (lc & 7) << 4;
      #pragma unroll
      for (int ks = 0; ks < 8; ++ks) {
        const bf16x8 fr = a[mf][ks];
        const int k0 = 32 * ks + 8 * l4;
        unsigned int pk[4];
        #pragma unroll
        for (int q = 0; q < 4; ++q) {
          float v0 = (-1.0f / 6.0f) * bf2f((unsigned short)fr[2 * q]);
          float v1 = (-1.0f / 6.0f) * bf2f((unsigned short)fr[2 * q + 1]);
          if (k0 + 2 * q == gcol) v0 += 1.0f;
          if (k0 + 2 * q + 1 == gcol) v1 += 1.0f;
          pk[q] = pk2bf(v0, v1);
        }
        const int byte = lc * 512 + ((2 * k0) ^ swz);
        uint4 val; val.x = pk[0]; val.y = pk[1]; val.z = pk[2]; val.w = pk[3];
        *(uint4*)(&Tl[0][byte]) = val;
      }
    }
  }
  __syncthreads();

  float* const outb = out + (size_t)b * NN * NN + cb * 64;
  const bool diagw = (wv == cb);

  #pragma unroll
  for (int it = 0; it < 5; ++it) {
    const int rd = it & 1;        // compile-time after unroll
    const int wr = rd ^ 1;
    const float coef = (it == 0) ? 0.2f : (it == 1) ? 0.25f : (it == 2) ? (1.0f / 3.0f)
                     : (it == 3) ? 0.5f : 1.0f;
    #pragma unroll
    for (int p = 0; p < 2; ++p) {
      // ---- explicit prefetch: ALL 16 B-fragments of this pass, issued back-to-back
      bf16x8 bfr[8][2];
      #pragma unroll
      for (int ks = 0; ks < 8; ++ks) {
        #pragma unroll
        for (int pn = 0; pn < 2; ++pn) {
          const int col = 16 * (2 * p + pn) + l15;
          const int byte = col * 512 + (((32 * ks + 8 * l4) * 2) ^ ((col & 7) << 4));
          bfr[ks][pn] = *(const bf16x8*)(&Tl[rd][byte]);
        }
      }

      f32x4 acc[4][2];
      #pragma unroll
      for (int mf = 0; mf < 4; ++mf)
        #pragma unroll
        for (int pn = 0; pn < 2; ++pn) {
          f32x4 z = {0.0f, 0.0f, 0.0f, 0.0f};
          acc[mf][pn] = z;
        }

      #pragma unroll
      for (int ks = 0; ks < 8; ++ks) {
        #pragma unroll
        for (int mf = 0; mf < 4; ++mf)
          #pragma unroll
          for (int pn = 0; pn < 2; ++pn)
            acc[mf][pn] = __builtin_amdgcn_mfma_f32_16x16x32_bf16(a[mf][ks], bfr[ks][pn], acc[mf][pn], 0, 0, 0);
      }

      if (it < 4) {
        // write this pass's T_new columns into the other buffer (no barrier needed:
        // reads target Tl[rd], writes target Tl[wr])
        #pragma unroll
        for (int mf = 0; mf < 4; ++mf) {
          #pragma unroll
          for (int pn = 0; pn < 2; ++pn) {
            const int nf = 2 * p + pn;
            const int col = 16 * nf + l15;
            const int row0l = 16 * mf + 4 * l4;
            float v0 = coef * acc[mf][pn][0];
            float v1 = coef * acc[mf][pn][1];
            float v2 = coef * acc[mf][pn][2];
            float v3 = coef * acc[mf][pn][3];
            if (diagw && mf == nf) {
              if (row0l + 0 == col) v0 += 1.0f;
              if (row0l + 1 == col) v1 += 1.0f;
              if (row0l + 2 == col) v2 += 1.0f;
              if (row0l + 3 == col) v3 += 1.0f;
            }
            const int byte = col * 512 + (((rbase + row0l) * 2) ^ ((col & 7) << 4));
            uint2 val; val.x = pk2bf(v0, v1); val.y = pk2bf(v2, v3);
            *(uint2*)(&Tl[wr][byte]) = val;
          }
        }
      } else {
        // final iteration: res = I + S*T in fp32 straight to global
        #pragma unroll
        for (int mf = 0; mf < 4; ++mf) {
          #pragma unroll
          for (int pn = 0; pn < 2; ++pn) {
            const int nf = 2 * p + pn;
            const int col = 16 * nf + l15;
            const int row0 = rbase + 16 * mf + 4 * l4;
            #pragma unroll
            for (int j = 0; j < 4; ++j) {
              float v = acc[mf][pn][j];
              if (diagw && mf == nf && (16 * mf + 4 * l4 + j == col)) v += 1.0f;
              outb[(size_t)(row0 + j) * NN + col] = v;
            }
          }
        }
      }
    }
    if (it < 4) __syncthreads();  // T_new complete before next iteration reads it
  }
}

extern "C" void kernel_launch(void* const* d_in, const int* in_sizes, int n_in,
                              void* d_out, int out_size, void* d_ws, size_t ws_size,
                              hipStream_t stream) {
  const float* w = (const float*)d_in[0];
  float* out = (float*)d_out;
  unsigned short* sws = (unsigned short*)d_ws;  // needs 512*256*256*2 = 64 MB
  skew_prep_kernel<<<dim3(NB * 10), dim3(256), 0, stream>>>(w, sws);
  expm_main_kernel<<<dim3(NB * 4), dim3(256), 0, stream>>>(sws, out);
}